// Round 8
// baseline (210.932 us; speedup 1.0000x reference)
//
#include <hip/hip_runtime.h>
#include <hip/hip_bf16.h>
#include <math.h>

#define NTHREADS 256
typedef __attribute__((ext_vector_type(8))) short short8;
typedef __attribute__((ext_vector_type(4))) float f32x4;
typedef unsigned short ushort_t;

// ---- conv kernel LDS: two time-major activation buffers hT[row=t+4][slot],
// 212 rows x stride 40 bf16 (bufA/bufB). Packed conv1 input X lives IN bufB
// at the SAME 40-slot stride, base HB (slots 0..29 = tap*6+ch; 30..39 zero).
// X rows 0..3 alias bufB's pad rows -> re-zeroed after conv1 (R5 lesson).
// FUSED TAIL float region after the hw buffers:
//   FL[192]  : conv4 output f (gelu'd)
//   ZP[4][52]: per-wave linear partials (reused by lin1/lin2/lin3)
//   Z1[52]   : gelu(linear1) (pads 50..51 zeroed)
//   Z2[52]   : gelu(linear2) (pads 50..51 zeroed)
// Total LDS 35,936 B <= 40,960 -> 4 blocks/CU.
#define HA    0
#define HB    8480
#define HSTR  40
// float-region offsets (in FLOAT units; byte 33920 == float 8480)
#define FLo   8480
#define ZPo   8672
#define Z1o   8880
#define Z2o   8932
#define SMEM_HW_TOT 17968     // 35,936 bytes

// ws layout: 27 conv A-frags bf16 (512 hw each) at 0;
// tail-weight blob float4[3245] at byte 65536:
//   [0..2400)  lw1s [j4][50] = lw1[c][4j4..+3]
//   [2400..3050) lw2s [j4][50] (tail j zero-padded)
//   [3050..3245) lw3s [j4][15] (tail j zero-padded)
// Z (z*100, 16 floats per item) at byte 131072.
#define WSF_C1 0
#define WSF_C2 (2*512)
#define WSF_C3 (12*512)
#define WSF_C4 (22*512)
#define WS_TWB_BYTE 65536
#define WS_Z_BYTE   131072

__device__ __forceinline__ unsigned f2bf(float f) {
    unsigned u = __float_as_uint(f);
    return (u + 0x7FFFu + ((u >> 16) & 1u)) >> 16;
}

// packed f32x2 -> bf16x2 RNE; on gfx950 lowers to v_cvt_pk_bf16_f32.
__device__ __forceinline__ unsigned pack2bf(float a, float b) {
    __hip_bfloat162 h = __float22bfloat162_rn(make_float2(a, b));
    unsigned u; __builtin_memcpy(&u, &h, 4); return u;
}

// tanh-GELU, minimal-op form: gelu = x - x/(exp2(x*t)+1).
__device__ __forceinline__ float gelu_fast(float x) {
    float x2 = x * x;
    float t  = fmaf(0.10294320f, x2, 2.3022082f);
    float e  = __builtin_amdgcn_exp2f(x * t);
    float r  = __builtin_amdgcn_rcpf(e + 1.0f);
    return fmaf(-x, r, x);
}

__device__ __forceinline__ float gelu_exact(float v) {
    return 0.5f * v * (1.0f + erff(v * 0.70710678118654752f));
}

#define JROT(Spp, Sqq, Spq, Sxp, Sxq, Vp0, Vq0, Vp1, Vq1, Vp2, Vq2)          \
    if (fabsf(Spq) > 1e-18f) {                                               \
        float tau = (Sqq - Spp) / (2.0f * Spq);                              \
        float tj = copysignf(1.0f, tau) / (fabsf(tau) + sqrtf(1.0f + tau*tau)); \
        float cj = 1.0f / sqrtf(1.0f + tj*tj);                               \
        float sj = tj * cj;                                                  \
        Spp -= tj * Spq; Sqq += tj * Spq; Spq = 0.0f;                        \
        float tmp0 = Sxp; Sxp = cj*tmp0 - sj*Sxq; Sxq = sj*tmp0 + cj*Sxq;    \
        float tv;                                                            \
        tv = Vp0; Vp0 = cj*tv - sj*Vq0; Vq0 = sj*tv + cj*Vq0;                \
        tv = Vp1; Vp1 = cj*tv - sj*Vq1; Vq1 = sj*tv + cj*Vq1;                \
        tv = Vp2; Vp2 = cj*tv - sj*Vq2; Vq2 = sj*tv + cj*Vq2;                \
    }

// ---- prep: conv weights -> MFMA A-frag lane order (bf16), fids 0..26.
// fids 27..33: repack tail linear weights into the contiguous float4 blob.
__global__ void prep_kernel(const float* __restrict__ cw1,
                            const float* __restrict__ cw2,
                            const float* __restrict__ cw3,
                            const float* __restrict__ cw4,
                            const float* __restrict__ lw1,
                            const float* __restrict__ lw2,
                            const float* __restrict__ lw3,
                            ushort_t* __restrict__ ws,
                            float4* __restrict__ twb)
{
    const int fid = blockIdx.x;              // 0..33
    if (fid >= 27) {                         // tail-weight repack
        const int idx = (fid - 27) * 512 + threadIdx.x;
        if (idx < 2400) {
            int j4 = idx / 50, c = idx - 50 * j4;
            const float* p = lw1 + c * 192 + 4 * j4;
            twb[idx] = make_float4(p[0], p[1], p[2], p[3]);
        } else if (idx < 3050) {
            int r = idx - 2400, j4 = r / 50, c = r - 50 * j4;
            const float* p = lw2 + c * 50 + 4 * j4;
            float4 w;
            w.x = p[0]; w.y = p[1];
            w.z = (4 * j4 + 2 < 50) ? p[2] : 0.0f;
            w.w = (4 * j4 + 3 < 50) ? p[3] : 0.0f;
            twb[idx] = w;
        } else if (idx < 3245) {
            int r = idx - 3050, j4 = r / 15, c = r - 15 * j4;
            const float* p = lw3 + c * 50 + 4 * j4;
            float4 w;
            w.x = p[0]; w.y = p[1];
            w.z = (4 * j4 + 2 < 50) ? p[2] : 0.0f;
            w.w = (4 * j4 + 3 < 50) ? p[3] : 0.0f;
            twb[idx] = w;
        }
        return;
    }
    const int l = threadIdx.x >> 3, j = threadIdx.x & 7;
    const int lo = l & 15, q = l >> 4;
    const int k = q * 8 + j;                 // 0..31
    const int pk = ((k >> 2) & 1) * 16 + (k >> 3) * 4 + (k & 3);  // slot->och
    float v = 0.0f;
    if (fid < 2) {                           // conv1 packed-K: t=k/6, c=k%6
        int m = fid * 16 + lo;
        if (k < 30) { int t = k / 6, c = k - 6 * t; v = cw1[(m * 6 + c) * 5 + t]; }
    } else if (fid < 12) {                   // conv2
        int f = fid - 2, tap = f >> 1, Mt = f & 1, m = Mt * 16 + lo;
        v = cw2[(m * 32 + pk) * 5 + tap];
    } else if (fid < 22) {                   // conv3
        int f = fid - 12, tap = f >> 1, Mt = f & 1, m = Mt * 16 + lo;
        v = cw3[(m * 32 + pk) * 5 + tap];
    } else {                                 // conv4: M-row 0 only
        int tap = fid - 22;
        if (lo == 0) v = cw4[pk * 5 + tap];
    }
    ws[fid * 512 + l * 8 + j] = (ushort_t)f2bf(v);
}

// Permuted-slot epilogue: one ds_write_b128 per lane (slots q*8..q*8+7).
template<bool EDGE>
__device__ __forceinline__ void store_tile(
    ushort_t* __restrict__ dst, const f32x4 a0, const f32x4 a1,
    int n, int Lout, int quad)
{
    ushort_t* row = dst + (4 + n) * HSTR + quad * 8;
    if (EDGE && n >= Lout) {
        *(uint4*)row = make_uint4(0u, 0u, 0u, 0u);
    } else {
        *(uint4*)row = make_uint4(
            pack2bf(gelu_fast(a0[0]), gelu_fast(a0[1])),
            pack2bf(gelu_fast(a0[2]), gelu_fast(a0[3])),
            pack2bf(gelu_fast(a1[0]), gelu_fast(a1[1])),
            pack2bf(gelu_fast(a1[2]), gelu_fast(a1[3])));
    }
}

// ---- conv2/3: 2 tiles (pair) or 1; 5 taps, dil=3. Only tile 12 (EDGEB)
// needs the row clamp / n<Lout guard.
template<bool TWO, bool EDGEB>
__device__ __forceinline__ void conv_tiles(
    const ushort_t* __restrict__ src, ushort_t* __restrict__ dst,
    const short8 A[5][2], f32x4 b0, f32x4 b1, int Lout,
    int lo16, int quad, int t0)
{
    f32x4 acc00 = b0, acc01 = b1, acc10 = b0, acc11 = b1;
    const int n0a = t0 * 16, n0b = (t0 + 4) * 16;
    const ushort_t* pa = src + (n0a + lo16) * HSTR + quad * 8;
    const ushort_t* pb = src + (n0b + lo16) * HSTR + quad * 8;
    #pragma unroll
    for (int t = 0; t < 5; t++) {
        short8 Ba = *(const short8*)(pa + 3 * HSTR * t);
        acc00 = __builtin_amdgcn_mfma_f32_16x16x32_bf16(A[t][0], Ba, acc00, 0, 0, 0);
        acc01 = __builtin_amdgcn_mfma_f32_16x16x32_bf16(A[t][1], Ba, acc01, 0, 0, 0);
        if (TWO) {
            short8 Bb;
            if (EDGEB) {
                int rb = min(n0b + lo16 + 3 * t, 211);   // clamp
                Bb = *(const short8*)(src + rb * HSTR + quad * 8);
            } else {
                Bb = *(const short8*)(pb + 3 * HSTR * t);
            }
            acc10 = __builtin_amdgcn_mfma_f32_16x16x32_bf16(A[t][0], Bb, acc10, 0, 0, 0);
            acc11 = __builtin_amdgcn_mfma_f32_16x16x32_bf16(A[t][1], Bb, acc11, 0, 0, 0);
        }
    }
    store_tile<false>(dst, acc00, acc01, n0a + lo16, Lout, quad);
    if (TWO) store_tile<EDGEB>(dst, acc10, acc11, n0b + lo16, Lout, quad);
}

// 13 tiles over 4 waves: wave0 {0,4} {8,12e}; wave w {w,w+4} {w+8}.
template<int LAYER>
__device__ __forceinline__ void conv_mfma(
    const ushort_t* __restrict__ src, ushort_t* __restrict__ dst,
    const ushort_t* __restrict__ wsf, const float* __restrict__ bias,
    int Lout, int lane, int wave)
{
    const int lo16 = lane & 15, quad = lane >> 4;
    short8 A[5][2];
    #pragma unroll
    for (int t = 0; t < 5; t++) {
        A[t][0] = *(const short8*)(wsf + (t * 2 + 0) * 512 + lane * 8);
        A[t][1] = *(const short8*)(wsf + (t * 2 + 1) * 512 + lane * 8);
    }
    f32x4 b0, b1;
    #pragma unroll
    for (int r = 0; r < 4; r++) { b0[r] = bias[quad * 4 + r]; b1[r] = bias[16 + quad * 4 + r]; }
    conv_tiles<true, false>(src, dst, A, b0, b1, Lout, lo16, quad, wave);
    if (wave == 0) conv_tiles<true, true>(src, dst, A, b0, b1, Lout, lo16, quad, 8);
    else           conv_tiles<false, false>(src, dst, A, b0, b1, Lout, lo16, quad, wave + 8);
}

// ---- conv1 packed-K: one B-read + 2 MFMA per tile (5 taps x 6 ch, K=30).
__device__ __forceinline__ void conv1_packed(
    const ushort_t* __restrict__ xb, ushort_t* __restrict__ dst,
    const ushort_t* __restrict__ wsf, const float* __restrict__ bias,
    int lane, int wave)
{
    const int lo16 = lane & 15, quad = lane >> 4;
    const short8 A0 = *(const short8*)(wsf + 0 * 512 + lane * 8);
    const short8 A1 = *(const short8*)(wsf + 1 * 512 + lane * 8);
    f32x4 b0, b1;
    #pragma unroll
    for (int r = 0; r < 4; r++) { b0[r] = bias[quad * 4 + r]; b1[r] = bias[16 + quad * 4 + r]; }
    f32x4 a0[3], a1[3];
    #pragma unroll
    for (int u = 0; u < 3; u++) {
        const int n = (wave + 4 * u) * 16 + lo16;
        short8 B = *(const short8*)(xb + n * HSTR + quad * 8);
        a0[u] = __builtin_amdgcn_mfma_f32_16x16x32_bf16(A0, B, b0, 0, 0, 0);
        a1[u] = __builtin_amdgcn_mfma_f32_16x16x32_bf16(A1, B, b1, 0, 0, 0);
    }
    #pragma unroll
    for (int u = 0; u < 3; u++)
        store_tile<false>(dst, a0[u], a1[u], (wave + 4 * u) * 16 + lo16, 204, quad);
    if (wave == 0) {                         // edge tile 12
        const int n = 192 + lo16;
        short8 B = *(const short8*)(xb + n * HSTR + quad * 8);
        f32x4 e0 = __builtin_amdgcn_mfma_f32_16x16x32_bf16(A0, B, b0, 0, 0, 0);
        f32x4 e1 = __builtin_amdgcn_mfma_f32_16x16x32_bf16(A1, B, b1, 0, 0, 0);
        store_tile<true>(dst, e0, e1, n, 204, quad);
    }
}

__global__ void __launch_bounds__(NTHREADS, 4)
rminet_conv_kernel(const float* __restrict__ x,
                   const float* __restrict__ calib,
                   const float* __restrict__ biasv,
                   const float* __restrict__ cb1, const float* __restrict__ cb2,
                   const float* __restrict__ cb3, const float* __restrict__ cb4,
                   const ushort_t* __restrict__ wsp,
                   const float4* __restrict__ twb,
                   const float* __restrict__ lb1,
                   const float* __restrict__ lb2,
                   const float* __restrict__ lb3,
                   float* __restrict__ Z)
{
    __shared__ __align__(16) ushort_t smh[SMEM_HW_TOT];
    float* smf = (float*)smh;
    const int tid  = threadIdx.x;
    const int b    = blockIdx.x;
    const int lane = tid & 63;
    const int wave = __builtin_amdgcn_readfirstlane(tid >> 6);

    // Zero: bufA pad rows 0..3 [0..19], bufA rows 200..211 [1000..1059],
    // ALL of bufB [1060..2119]. MFMA 0*NaN = NaN; every readable byte inits.
    {
        uint4* p = (uint4*)smh;
        for (int i = tid; i < 1140; i += NTHREADS) {
            int idx = (i < 20) ? i : ((i < 80) ? 1000 + (i - 20) : 1060 + (i - 80));
            p[idx] = make_uint4(0u, 0u, 0u, 0u);
        }
    }
    __syncthreads();

    // calibrate + normalize -> packed X rows IN bufB (stride HSTR=40).
    if (tid < 200) {
        const float* xc = x + (size_t)b * 1400 + 200 + tid;
        float v[6];
        #pragma unroll
        for (int ch = 0; ch < 6; ch++) v[ch] = xc[ch * 200];
        const float MEANS[6]  = {0.042766f, 0.0081577f, -0.015818f, 9.2993f, -0.087913f, -3.3231f};
        const float INVSTD[6] = {1.f/0.4142f, 1.f/0.3522f, 1.f/0.2881f, 1.f/1.474f, 1.f/0.6553f, 1.f/0.8728f};
        float xn[6];
        #pragma unroll
        for (int i = 0; i < 6; i++) {
            float acc = biasv[i];
            #pragma unroll
            for (int jj = 0; jj < 6; jj++) {
                float m = calib[i * 6 + jj] + ((i == jj) ? 1.0f : 0.0f);
                acc = fmaf(m, v[jj], acc);
            }
            xn[i] = (acc - MEANS[i]) * INVSTD[i];
        }
        const unsigned d0 = pack2bf(xn[0], xn[1]);
        const unsigned d1 = pack2bf(xn[2], xn[3]);
        const unsigned d2 = pack2bf(xn[4], xn[5]);
        const int trot = tid & 3;
        #pragma unroll
        for (int tt = 0; tt < 5; tt++) {
            int t = tt + trot; if (t >= 5) t -= 5;
            ushort_t* qp = smh + HB + (tid + 4 - t) * HSTR + t * 6;
            *(unsigned*)(qp + 0) = d0;
            *(unsigned*)(qp + 2) = d1;
            *(unsigned*)(qp + 4) = d2;
        }
    }
    __syncthreads();

    conv1_packed(smh + HB, smh + HA, wsp + WSF_C1, cb1, lane, wave);
    __syncthreads();
    // X consumed. Re-zero bufB rows 0..3 (stale X aliases conv3's left pad;
    // R5's bug). Disjoint from conv2's writes; ordered by the next barrier.
    if (tid < 20) ((uint4*)smh)[1060 + tid] = make_uint4(0u, 0u, 0u, 0u);
    conv_mfma<2>(smh + HA, smh + HB, wsp + WSF_C2, cb2, 200, lane, wave);
    __syncthreads();
    conv_mfma<3>(smh + HB, smh + HA, wsp + WSF_C3, cb3, 196, lane, wave);
    // Re-zero bufA rows 200..203 before conv4 (stale-h1 guard).
    if (tid < 20) ((uint4*)smh)[1000 + tid] = make_uint4(0u, 0u, 0u, 0u);
    __syncthreads();

    // conv4 (MFMA, M-row 0 only): h3 -> FL[192] in LDS (fused; no global F).
    {
        const int lo16 = lane & 15, quad = lane >> 4;
        short8 A4[5];
        #pragma unroll
        for (int t = 0; t < 5; t++)
            A4[t] = *(const short8*)(wsp + WSF_C4 + t * 512 + lane * 8);
        f32x4 acc[3];
        #pragma unroll
        for (int u = 0; u < 3; u++) acc[u] = (f32x4){0.f, 0.f, 0.f, 0.f};
        const ushort_t* p4[3];
        #pragma unroll
        for (int u = 0; u < 3; u++)
            p4[u] = smh + HA + ((wave + 4 * u) * 16 + lo16) * HSTR + quad * 8;
        #pragma unroll
        for (int t = 0; t < 5; t++) {
            #pragma unroll
            for (int u = 0; u < 3; u++) {
                short8 B = *(const short8*)(p4[u] + 3 * HSTR * t);   // row <= 203
                acc[u] = __builtin_amdgcn_mfma_f32_16x16x32_bf16(A4[t], B, acc[u], 0, 0, 0);
            }
        }
        if (quad == 0) {
            const float c4 = cb4[0];
            #pragma unroll
            for (int u = 0; u < 3; u++) {
                int n = (wave + 4 * u) * 16 + lo16;
                smf[FLo + n] = gelu_fast(acc[u][0] + c4);
            }
        }
    }
    __syncthreads();

    // ---- fused tail, ALL phases K-split across the 4 waves (R7's wave-0-only
    // linear2/3 was the +18us regression: 26 serial L2-latency-bound
    // iterations on one wave while 3 idled).
    // Phase A: linear1 partials (48 j4 = 12/wave).
    {
        const int c = (lane < 50) ? lane : 49;
        float a = (wave == 0) ? lb1[c] : 0.0f;
        const int j0 = wave * 12;
        #pragma unroll
        for (int j4 = 0; j4 < 12; j4++) {
            float4 w = twb[(j0 + j4) * 50 + c];
            float4 f = *(const float4*)&smf[FLo + (j0 + j4) * 4];
            a = fmaf(w.x, f.x, fmaf(w.y, f.y, fmaf(w.z, f.z, fmaf(w.w, f.w, a))));
        }
        if (lane < 50) smf[ZPo + wave * 52 + lane] = a;
    }
    __syncthreads();

    // Phase B: reduce + gelu -> Z1 (wave 0; 50 parallel lanes, cheap).
    if (wave == 0) {
        if (lane < 50) {
            float s = smf[ZPo + lane] + smf[ZPo + 52 + lane]
                    + smf[ZPo + 104 + lane] + smf[ZPo + 156 + lane];
            smf[Z1o + lane] = gelu_exact(s);
        }
        if (lane == 50 || lane == 51) smf[Z1o + lane] = 0.0f;
    }
    __syncthreads();

    // Phase C: linear2 partials, 13 j4 split {w,w+4,w+8} + wave0 j4=12.
    {
        const int c = (lane < 50) ? lane : 49;
        float a = (wave == 0) ? lb2[c] : 0.0f;
        #pragma unroll
        for (int u = 0; u < 3; u++) {
            int j4 = wave + 4 * u;
            float4 w = twb[2400 + j4 * 50 + c];
            float4 zp = *(const float4*)&smf[Z1o + 4 * j4];
            a = fmaf(w.x, zp.x, fmaf(w.y, zp.y, fmaf(w.z, zp.z, fmaf(w.w, zp.w, a))));
        }
        if (wave == 0) {
            float4 w = twb[2400 + 12 * 50 + c];
            float4 zp = *(const float4*)&smf[Z1o + 48];
            a = fmaf(w.x, zp.x, fmaf(w.y, zp.y, fmaf(w.z, zp.z, fmaf(w.w, zp.w, a))));
        }
        if (lane < 50) smf[ZPo + wave * 52 + lane] = a;
    }
    __syncthreads();

    // Phase D: reduce + gelu -> Z2.
    if (wave == 0) {
        if (lane < 50) {
            float s = smf[ZPo + lane] + smf[ZPo + 52 + lane]
                    + smf[ZPo + 104 + lane] + smf[ZPo + 156 + lane];
            smf[Z2o + lane] = gelu_exact(s);
        }
        if (lane == 50 || lane == 51) smf[Z2o + lane] = 0.0f;
    }
    __syncthreads();

    // Phase E: linear3 partials (15 outputs), same 13-j4 split.
    {
        const int c3 = (lane < 15) ? lane : 14;
        float a = (wave == 0) ? lb3[c3] : 0.0f;
        #pragma unroll
        for (int u = 0; u < 3; u++) {
            int j4 = wave + 4 * u;
            float4 w = twb[3050 + j4 * 15 + c3];
            float4 zp = *(const float4*)&smf[Z2o + 4 * j4];
            a = fmaf(w.x, zp.x, fmaf(w.y, zp.y, fmaf(w.z, zp.z, fmaf(w.w, zp.w, a))));
        }
        if (wave == 0) {
            float4 w = twb[3050 + 12 * 15 + c3];
            float4 zp = *(const float4*)&smf[Z2o + 48];
            a = fmaf(w.x, zp.x, fmaf(w.y, zp.y, fmaf(w.z, zp.z, fmaf(w.w, zp.w, a))));
        }
        if (lane < 15) smf[ZPo + wave * 52 + lane] = a;
    }
    __syncthreads();

    // Phase F: final reduce, *100 -> Z.
    if (wave == 0 && lane < 15) {
        float s = smf[ZPo + lane] + smf[ZPo + 52 + lane]
                + smf[ZPo + 104 + lane] + smf[ZPo + 156 + lane];
        Z[(size_t)b * 16 + lane] = s * 100.0f;
    }
}

// ---- SVD kernel: ONE LANE PER ITEM (fully parallel Jacobi).
// 8192 items -> 32 blocks x 256.
__global__ void __launch_bounds__(256)
rminet_svd_kernel(const float* __restrict__ Z, float* __restrict__ out, int B)
{
    const int i = blockIdx.x * 256 + threadIdx.x;
    if (i >= B) return;
    const float* zv = Z + (size_t)i * 16;
    float* ob = out + (size_t)i * 15;
    #pragma unroll
    for (int c = 9; c < 15; c++) ob[c] = zv[c];

    const float A00 = zv[0], A01 = zv[1], A02 = zv[2];
    const float A10 = zv[3], A11 = zv[4], A12 = zv[5];
    const float A20 = zv[6], A21 = zv[7], A22 = zv[8];
    float S00 = A00*A00 + A10*A10 + A20*A20;
    float S01 = A00*A01 + A10*A11 + A20*A21;
    float S02 = A00*A02 + A10*A12 + A20*A22;
    float S11 = A01*A01 + A11*A11 + A21*A21;
    float S12 = A01*A02 + A11*A12 + A21*A22;
    float S22 = A02*A02 + A12*A12 + A22*A22;
    float V00=1.f, V01=0.f, V02=0.f;
    float V10=0.f, V11=1.f, V12=0.f;
    float V20=0.f, V21=0.f, V22=1.f;
    #pragma unroll
    for (int sweep = 0; sweep < 8; sweep++) {
        JROT(S00, S11, S01, S02, S12, V00, V01, V10, V11, V20, V21)
        JROT(S00, S22, S02, S01, S12, V00, V02, V10, V12, V20, V22)
        JROT(S11, S22, S12, S01, S02, V01, V02, V11, V12, V21, V22)
    }
    float e0 = S00, e1 = S11, e2 = S22;
    float va0=V00, va1=V10, va2=V20;
    float vb0=V01, vb1=V11, vb2=V21;
    float vc0=V02, vc1=V12, vc2=V22;
    float sgn = 1.0f, tq;
    if (e0 < e1) { tq=e0;e0=e1;e1=tq; tq=va0;va0=vb0;vb0=tq; tq=va1;va1=vb1;vb1=tq; tq=va2;va2=vb2;vb2=tq; sgn=-sgn; }
    if (e1 < e2) { tq=e1;e1=e2;e2=tq; tq=vb0;vb0=vc0;vc0=tq; tq=vb1;vb1=vc1;vc1=tq; tq=vb2;vb2=vc2;vc2=tq; sgn=-sgn; }
    if (e0 < e1) { tq=e0;e0=e1;e1=tq; tq=va0;va0=vb0;vb0=tq; tq=va1;va1=vb1;vb1=tq; tq=va2;va2=vb2;vb2=tq; sgn=-sgn; }
    vc0 *= sgn; vc1 *= sgn; vc2 *= sgn;
    float u10 = A00*va0 + A01*va1 + A02*va2;
    float u11 = A10*va0 + A11*va1 + A12*va2;
    float u12 = A20*va0 + A21*va1 + A22*va2;
    float n1 = sqrtf(u10*u10 + u11*u11 + u12*u12);
    float rn1 = (n1 > 1e-20f) ? 1.0f / n1 : 0.0f;
    u10 *= rn1; u11 *= rn1; u12 *= rn1;
    float u20 = A00*vb0 + A01*vb1 + A02*vb2;
    float u21 = A10*vb0 + A11*vb1 + A12*vb2;
    float u22 = A20*vb0 + A21*vb1 + A22*vb2;
    float d12 = u20*u10 + u21*u11 + u22*u12;
    u20 -= d12*u10; u21 -= d12*u11; u22 -= d12*u12;
    float n2 = sqrtf(u20*u20 + u21*u21 + u22*u22);
    float rn2 = (n2 > 1e-20f) ? 1.0f / n2 : 0.0f;
    u20 *= rn2; u21 *= rn2; u22 *= rn2;
    float u30 = u11*u22 - u12*u21;
    float u31 = u12*u20 - u10*u22;
    float u32 = u10*u21 - u11*u20;
    ob[0] = u10*va0 + u20*vb0 + u30*vc0;
    ob[1] = u10*va1 + u20*vb1 + u30*vc1;
    ob[2] = u10*va2 + u20*vb2 + u30*vc2;
    ob[3] = u11*va0 + u21*vb0 + u31*vc0;
    ob[4] = u11*va1 + u21*vb1 + u31*vc1;
    ob[5] = u11*va2 + u21*vb2 + u31*vc2;
    ob[6] = u12*va0 + u22*vb0 + u32*vc0;
    ob[7] = u12*va1 + u22*vb1 + u32*vc1;
    ob[8] = u12*va2 + u22*vb2 + u32*vc2;
}

extern "C" void kernel_launch(void* const* d_in, const int* in_sizes, int n_in,
                              void* d_out, int out_size, void* d_ws, size_t ws_size,
                              hipStream_t stream) {
    (void)n_in; (void)out_size; (void)ws_size;
    const float* x     = (const float*)d_in[0];
    const float* calib = (const float*)d_in[1];
    const float* biasv = (const float*)d_in[2];
    const float* cw1   = (const float*)d_in[3];
    const float* cb1   = (const float*)d_in[4];
    const float* cw2   = (const float*)d_in[5];
    const float* cb2   = (const float*)d_in[6];
    const float* cw3   = (const float*)d_in[7];
    const float* cb3   = (const float*)d_in[8];
    const float* cw4   = (const float*)d_in[9];
    const float* cb4   = (const float*)d_in[10];
    const float* lw1   = (const float*)d_in[11];
    const float* lb1   = (const float*)d_in[12];
    const float* lw2   = (const float*)d_in[13];
    const float* lb2   = (const float*)d_in[14];
    const float* lw3   = (const float*)d_in[15];
    const float* lb3   = (const float*)d_in[16];
    float* out = (float*)d_out;
    ushort_t* wsh = (ushort_t*)d_ws;
    float4* twb = (float4*)((char*)d_ws + WS_TWB_BYTE);
    float* Zb   = (float*)((char*)d_ws + WS_Z_BYTE);
    const int B = in_sizes[0] / 1400;

    hipLaunchKernelGGL(prep_kernel, dim3(34), dim3(512), 0, stream,
                       cw1, cw2, cw3, cw4, lw1, lw2, lw3, wsh, twb);
    hipLaunchKernelGGL(rminet_conv_kernel, dim3(B), dim3(NTHREADS), 0, stream,
                       x, calib, biasv, cb1, cb2, cb3, cb4,
                       (const ushort_t*)wsh, (const float4*)twb,
                       lb1, lb2, lb3, Zb);
    hipLaunchKernelGGL(rminet_svd_kernel, dim3((B + 255) / 256), dim3(256), 0, stream,
                       (const float*)Zb, out, B);
}

// Round 11
// 206.776 us; speedup vs baseline: 1.0201x; 1.0201x over previous
//
#include <hip/hip_runtime.h>
#include <hip/hip_bf16.h>
#include <math.h>

// REVERT (R10): byte-identical restore of the Round-7 passing configuration
// (206.3 us, absmax 0.038). The R9/R10 fused-SVD + weight-hoist variants both
// failed correctness (~1.7 absmax) with a mechanism that survived two rounds
// of inspection (fences + full barrier did not fix it) — experiment closed.

#define NTHREADS 256
typedef __attribute__((ext_vector_type(8))) short short8;
typedef __attribute__((ext_vector_type(4))) float f32x4;
typedef unsigned short ushort_t;

// ---- conv kernel LDS: two time-major activation buffers hT[row=t+4][slot],
// 212 rows x stride 40 bf16 (bufA/bufB). Packed conv1 input X lives IN bufB
// at the SAME 40-slot stride, base HB (slots 0..29 = tap*6+ch; 30..39 zero).
// X rows 0..3 alias bufB's pad rows -> re-zeroed after conv1 (R5 lesson).
// FUSED TAIL float region after the hw buffers:
//   FL[192]  : conv4 output f (gelu'd)
//   ZP[4][52]: per-wave linear1 partials
//   Z1[52]   : gelu(linear1) (pads 50..51 zeroed)
//   Z2[52]   : gelu(linear2) (pads 50..51 zeroed)
// Total LDS 35,936 B <= 40,960 -> 4 blocks/CU.
#define HA    0
#define HB    8480
#define HSTR  40
// float-region offsets (in FLOAT units; byte 33920 == float 8480)
#define FLo   8480
#define ZPo   8672
#define Z1o   8880
#define Z2o   8932
#define SMEM_HW_TOT 17968     // 35,936 bytes

// ws layout: 27 conv A-frags bf16 (512 hw each) at 0;
// tail-weight blob float4[3245] at byte 65536:
//   [0..2400)  lw1s [j4][50] = lw1[c][4j4..+3]
//   [2400..3050) lw2s [j4][50] (tail j zero-padded)
//   [3050..3245) lw3s [j4][15] (tail j zero-padded)
// Z (z*100, 16 floats per item) at byte 131072.
#define WSF_C1 0
#define WSF_C2 (2*512)
#define WSF_C3 (12*512)
#define WSF_C4 (22*512)
#define WS_TWB_BYTE 65536
#define WS_Z_BYTE   131072

__device__ __forceinline__ unsigned f2bf(float f) {
    unsigned u = __float_as_uint(f);
    return (u + 0x7FFFu + ((u >> 16) & 1u)) >> 16;
}

// packed f32x2 -> bf16x2 RNE; on gfx950 lowers to v_cvt_pk_bf16_f32.
__device__ __forceinline__ unsigned pack2bf(float a, float b) {
    __hip_bfloat162 h = __float22bfloat162_rn(make_float2(a, b));
    unsigned u; __builtin_memcpy(&u, &h, 4); return u;
}

// tanh-GELU, minimal-op form: gelu = x - x/(exp2(x*t)+1).
__device__ __forceinline__ float gelu_fast(float x) {
    float x2 = x * x;
    float t  = fmaf(0.10294320f, x2, 2.3022082f);
    float e  = __builtin_amdgcn_exp2f(x * t);
    float r  = __builtin_amdgcn_rcpf(e + 1.0f);
    return fmaf(-x, r, x);
}

__device__ __forceinline__ float gelu_exact(float v) {
    return 0.5f * v * (1.0f + erff(v * 0.70710678118654752f));
}

#define JROT(Spp, Sqq, Spq, Sxp, Sxq, Vp0, Vq0, Vp1, Vq1, Vp2, Vq2)          \
    if (fabsf(Spq) > 1e-18f) {                                               \
        float tau = (Sqq - Spp) / (2.0f * Spq);                              \
        float tj = copysignf(1.0f, tau) / (fabsf(tau) + sqrtf(1.0f + tau*tau)); \
        float cj = 1.0f / sqrtf(1.0f + tj*tj);                               \
        float sj = tj * cj;                                                  \
        Spp -= tj * Spq; Sqq += tj * Spq; Spq = 0.0f;                        \
        float tmp0 = Sxp; Sxp = cj*tmp0 - sj*Sxq; Sxq = sj*tmp0 + cj*Sxq;    \
        float tv;                                                            \
        tv = Vp0; Vp0 = cj*tv - sj*Vq0; Vq0 = sj*tv + cj*Vq0;                \
        tv = Vp1; Vp1 = cj*tv - sj*Vq1; Vq1 = sj*tv + cj*Vq1;                \
        tv = Vp2; Vp2 = cj*tv - sj*Vq2; Vq2 = sj*tv + cj*Vq2;                \
    }

// ---- prep: conv weights -> MFMA A-frag lane order (bf16), fids 0..26.
// fids 27..33: repack tail linear weights into the contiguous float4 blob.
__global__ void prep_kernel(const float* __restrict__ cw1,
                            const float* __restrict__ cw2,
                            const float* __restrict__ cw3,
                            const float* __restrict__ cw4,
                            const float* __restrict__ lw1,
                            const float* __restrict__ lw2,
                            const float* __restrict__ lw3,
                            ushort_t* __restrict__ ws,
                            float4* __restrict__ twb)
{
    const int fid = blockIdx.x;              // 0..33
    if (fid >= 27) {                         // tail-weight repack
        const int idx = (fid - 27) * 512 + threadIdx.x;
        if (idx < 2400) {
            int j4 = idx / 50, c = idx - 50 * j4;
            const float* p = lw1 + c * 192 + 4 * j4;
            twb[idx] = make_float4(p[0], p[1], p[2], p[3]);
        } else if (idx < 3050) {
            int r = idx - 2400, j4 = r / 50, c = r - 50 * j4;
            const float* p = lw2 + c * 50 + 4 * j4;
            float4 w;
            w.x = p[0]; w.y = p[1];
            w.z = (4 * j4 + 2 < 50) ? p[2] : 0.0f;
            w.w = (4 * j4 + 3 < 50) ? p[3] : 0.0f;
            twb[idx] = w;
        } else if (idx < 3245) {
            int r = idx - 3050, j4 = r / 15, c = r - 15 * j4;
            const float* p = lw3 + c * 50 + 4 * j4;
            float4 w;
            w.x = p[0]; w.y = p[1];
            w.z = (4 * j4 + 2 < 50) ? p[2] : 0.0f;
            w.w = (4 * j4 + 3 < 50) ? p[3] : 0.0f;
            twb[idx] = w;
        }
        return;
    }
    const int l = threadIdx.x >> 3, j = threadIdx.x & 7;
    const int lo = l & 15, q = l >> 4;
    const int k = q * 8 + j;                 // 0..31
    const int pk = ((k >> 2) & 1) * 16 + (k >> 3) * 4 + (k & 3);  // slot->och
    float v = 0.0f;
    if (fid < 2) {                           // conv1 packed-K: t=k/6, c=k%6
        int m = fid * 16 + lo;
        if (k < 30) { int t = k / 6, c = k - 6 * t; v = cw1[(m * 6 + c) * 5 + t]; }
    } else if (fid < 12) {                   // conv2
        int f = fid - 2, tap = f >> 1, Mt = f & 1, m = Mt * 16 + lo;
        v = cw2[(m * 32 + pk) * 5 + tap];
    } else if (fid < 22) {                   // conv3
        int f = fid - 12, tap = f >> 1, Mt = f & 1, m = Mt * 16 + lo;
        v = cw3[(m * 32 + pk) * 5 + tap];
    } else {                                 // conv4: M-row 0 only
        int tap = fid - 22;
        if (lo == 0) v = cw4[pk * 5 + tap];
    }
    ws[fid * 512 + l * 8 + j] = (ushort_t)f2bf(v);
}

// Permuted-slot epilogue: one ds_write_b128 per lane (slots q*8..q*8+7).
template<bool EDGE>
__device__ __forceinline__ void store_tile(
    ushort_t* __restrict__ dst, const f32x4 a0, const f32x4 a1,
    int n, int Lout, int quad)
{
    ushort_t* row = dst + (4 + n) * HSTR + quad * 8;
    if (EDGE && n >= Lout) {
        *(uint4*)row = make_uint4(0u, 0u, 0u, 0u);
    } else {
        *(uint4*)row = make_uint4(
            pack2bf(gelu_fast(a0[0]), gelu_fast(a0[1])),
            pack2bf(gelu_fast(a0[2]), gelu_fast(a0[3])),
            pack2bf(gelu_fast(a1[0]), gelu_fast(a1[1])),
            pack2bf(gelu_fast(a1[2]), gelu_fast(a1[3])));
    }
}

// ---- conv2/3: 2 tiles (pair) or 1; 5 taps, dil=3. Only tile 12 (EDGEB)
// needs the row clamp / n<Lout guard.
template<bool TWO, bool EDGEB>
__device__ __forceinline__ void conv_tiles(
    const ushort_t* __restrict__ src, ushort_t* __restrict__ dst,
    const short8 A[5][2], f32x4 b0, f32x4 b1, int Lout,
    int lo16, int quad, int t0)
{
    f32x4 acc00 = b0, acc01 = b1, acc10 = b0, acc11 = b1;
    const int n0a = t0 * 16, n0b = (t0 + 4) * 16;
    const ushort_t* pa = src + (n0a + lo16) * HSTR + quad * 8;
    const ushort_t* pb = src + (n0b + lo16) * HSTR + quad * 8;
    #pragma unroll
    for (int t = 0; t < 5; t++) {
        short8 Ba = *(const short8*)(pa + 3 * HSTR * t);
        acc00 = __builtin_amdgcn_mfma_f32_16x16x32_bf16(A[t][0], Ba, acc00, 0, 0, 0);
        acc01 = __builtin_amdgcn_mfma_f32_16x16x32_bf16(A[t][1], Ba, acc01, 0, 0, 0);
        if (TWO) {
            short8 Bb;
            if (EDGEB) {
                int rb = min(n0b + lo16 + 3 * t, 211);   // clamp
                Bb = *(const short8*)(src + rb * HSTR + quad * 8);
            } else {
                Bb = *(const short8*)(pb + 3 * HSTR * t);
            }
            acc10 = __builtin_amdgcn_mfma_f32_16x16x32_bf16(A[t][0], Bb, acc10, 0, 0, 0);
            acc11 = __builtin_amdgcn_mfma_f32_16x16x32_bf16(A[t][1], Bb, acc11, 0, 0, 0);
        }
    }
    store_tile<false>(dst, acc00, acc01, n0a + lo16, Lout, quad);
    if (TWO) store_tile<EDGEB>(dst, acc10, acc11, n0b + lo16, Lout, quad);
}

// 13 tiles over 4 waves: wave0 {0,4} {8,12e}; wave w {w,w+4} {w+8}.
template<int LAYER>
__device__ __forceinline__ void conv_mfma(
    const ushort_t* __restrict__ src, ushort_t* __restrict__ dst,
    const ushort_t* __restrict__ wsf, const float* __restrict__ bias,
    int Lout, int lane, int wave)
{
    const int lo16 = lane & 15, quad = lane >> 4;
    short8 A[5][2];
    #pragma unroll
    for (int t = 0; t < 5; t++) {
        A[t][0] = *(const short8*)(wsf + (t * 2 + 0) * 512 + lane * 8);
        A[t][1] = *(const short8*)(wsf + (t * 2 + 1) * 512 + lane * 8);
    }
    f32x4 b0, b1;
    #pragma unroll
    for (int r = 0; r < 4; r++) { b0[r] = bias[quad * 4 + r]; b1[r] = bias[16 + quad * 4 + r]; }
    conv_tiles<true, false>(src, dst, A, b0, b1, Lout, lo16, quad, wave);
    if (wave == 0) conv_tiles<true, true>(src, dst, A, b0, b1, Lout, lo16, quad, 8);
    else           conv_tiles<false, false>(src, dst, A, b0, b1, Lout, lo16, quad, wave + 8);
}

// ---- conv1 packed-K: one B-read + 2 MFMA per tile (5 taps x 6 ch, K=30).
__device__ __forceinline__ void conv1_packed(
    const ushort_t* __restrict__ xb, ushort_t* __restrict__ dst,
    const ushort_t* __restrict__ wsf, const float* __restrict__ bias,
    int lane, int wave)
{
    const int lo16 = lane & 15, quad = lane >> 4;
    const short8 A0 = *(const short8*)(wsf + 0 * 512 + lane * 8);
    const short8 A1 = *(const short8*)(wsf + 1 * 512 + lane * 8);
    f32x4 b0, b1;
    #pragma unroll
    for (int r = 0; r < 4; r++) { b0[r] = bias[quad * 4 + r]; b1[r] = bias[16 + quad * 4 + r]; }
    f32x4 a0[3], a1[3];
    #pragma unroll
    for (int u = 0; u < 3; u++) {
        const int n = (wave + 4 * u) * 16 + lo16;
        short8 B = *(const short8*)(xb + n * HSTR + quad * 8);
        a0[u] = __builtin_amdgcn_mfma_f32_16x16x32_bf16(A0, B, b0, 0, 0, 0);
        a1[u] = __builtin_amdgcn_mfma_f32_16x16x32_bf16(A1, B, b1, 0, 0, 0);
    }
    #pragma unroll
    for (int u = 0; u < 3; u++)
        store_tile<false>(dst, a0[u], a1[u], (wave + 4 * u) * 16 + lo16, 204, quad);
    if (wave == 0) {                         // edge tile 12
        const int n = 192 + lo16;
        short8 B = *(const short8*)(xb + n * HSTR + quad * 8);
        f32x4 e0 = __builtin_amdgcn_mfma_f32_16x16x32_bf16(A0, B, b0, 0, 0, 0);
        f32x4 e1 = __builtin_amdgcn_mfma_f32_16x16x32_bf16(A1, B, b1, 0, 0, 0);
        store_tile<true>(dst, e0, e1, n, 204, quad);
    }
}

__global__ void __launch_bounds__(NTHREADS, 4)
rminet_conv_kernel(const float* __restrict__ x,
                   const float* __restrict__ calib,
                   const float* __restrict__ biasv,
                   const float* __restrict__ cb1, const float* __restrict__ cb2,
                   const float* __restrict__ cb3, const float* __restrict__ cb4,
                   const ushort_t* __restrict__ wsp,
                   const float4* __restrict__ twb,
                   const float* __restrict__ lb1,
                   const float* __restrict__ lb2,
                   const float* __restrict__ lb3,
                   float* __restrict__ Z)
{
    __shared__ __align__(16) ushort_t smh[SMEM_HW_TOT];
    float* smf = (float*)smh;
    const int tid  = threadIdx.x;
    const int b    = blockIdx.x;
    const int lane = tid & 63;
    const int wave = __builtin_amdgcn_readfirstlane(tid >> 6);

    // Zero: bufA pad rows 0..3 [0..19], bufA rows 200..211 [1000..1059],
    // ALL of bufB [1060..2119]. MFMA 0*NaN = NaN; every readable byte inits.
    {
        uint4* p = (uint4*)smh;
        for (int i = tid; i < 1140; i += NTHREADS) {
            int idx = (i < 20) ? i : ((i < 80) ? 1000 + (i - 20) : 1060 + (i - 80));
            p[idx] = make_uint4(0u, 0u, 0u, 0u);
        }
    }
    __syncthreads();

    // calibrate + normalize -> packed X rows IN bufB (stride HSTR=40).
    if (tid < 200) {
        const float* xc = x + (size_t)b * 1400 + 200 + tid;
        float v[6];
        #pragma unroll
        for (int ch = 0; ch < 6; ch++) v[ch] = xc[ch * 200];
        const float MEANS[6]  = {0.042766f, 0.0081577f, -0.015818f, 9.2993f, -0.087913f, -3.3231f};
        const float INVSTD[6] = {1.f/0.4142f, 1.f/0.3522f, 1.f/0.2881f, 1.f/1.474f, 1.f/0.6553f, 1.f/0.8728f};
        float xn[6];
        #pragma unroll
        for (int i = 0; i < 6; i++) {
            float acc = biasv[i];
            #pragma unroll
            for (int jj = 0; jj < 6; jj++) {
                float m = calib[i * 6 + jj] + ((i == jj) ? 1.0f : 0.0f);
                acc = fmaf(m, v[jj], acc);
            }
            xn[i] = (acc - MEANS[i]) * INVSTD[i];
        }
        const unsigned d0 = pack2bf(xn[0], xn[1]);
        const unsigned d1 = pack2bf(xn[2], xn[3]);
        const unsigned d2 = pack2bf(xn[4], xn[5]);
        const int trot = tid & 3;
        #pragma unroll
        for (int tt = 0; tt < 5; tt++) {
            int t = tt + trot; if (t >= 5) t -= 5;
            ushort_t* qp = smh + HB + (tid + 4 - t) * HSTR + t * 6;
            *(unsigned*)(qp + 0) = d0;
            *(unsigned*)(qp + 2) = d1;
            *(unsigned*)(qp + 4) = d2;
        }
    }
    __syncthreads();

    conv1_packed(smh + HB, smh + HA, wsp + WSF_C1, cb1, lane, wave);
    __syncthreads();
    // X consumed. Re-zero bufB rows 0..3 (stale X aliases conv3's left pad;
    // R5's bug). Disjoint from conv2's writes; ordered by the next barrier.
    if (tid < 20) ((uint4*)smh)[1060 + tid] = make_uint4(0u, 0u, 0u, 0u);
    conv_mfma<2>(smh + HA, smh + HB, wsp + WSF_C2, cb2, 200, lane, wave);
    __syncthreads();
    conv_mfma<3>(smh + HB, smh + HA, wsp + WSF_C3, cb3, 196, lane, wave);
    // Re-zero bufA rows 200..203 before conv4 (stale-h1 guard).
    if (tid < 20) ((uint4*)smh)[1000 + tid] = make_uint4(0u, 0u, 0u, 0u);
    __syncthreads();

    // conv4 (MFMA, M-row 0 only): h3 -> FL[192] in LDS (fused; no global F).
    {
        const int lo16 = lane & 15, quad = lane >> 4;
        short8 A4[5];
        #pragma unroll
        for (int t = 0; t < 5; t++)
            A4[t] = *(const short8*)(wsp + WSF_C4 + t * 512 + lane * 8);
        f32x4 acc[3];
        #pragma unroll
        for (int u = 0; u < 3; u++) acc[u] = (f32x4){0.f, 0.f, 0.f, 0.f};
        const ushort_t* p4[3];
        #pragma unroll
        for (int u = 0; u < 3; u++)
            p4[u] = smh + HA + ((wave + 4 * u) * 16 + lo16) * HSTR + quad * 8;
        #pragma unroll
        for (int t = 0; t < 5; t++) {
            #pragma unroll
            for (int u = 0; u < 3; u++) {
                short8 B = *(const short8*)(p4[u] + 3 * HSTR * t);   // row <= 203
                acc[u] = __builtin_amdgcn_mfma_f32_16x16x32_bf16(A4[t], B, acc[u], 0, 0, 0);
            }
        }
        if (quad == 0) {
            const float c4 = cb4[0];
            #pragma unroll
            for (int u = 0; u < 3; u++) {
                int n = (wave + 4 * u) * 16 + lo16;
                smf[FLo + n] = gelu_fast(acc[u][0] + c4);
            }
        }
    }
    __syncthreads();

    // ---- fused tail: linear1 K-split across the 4 waves (48 each).
    // Weights stream coalesced from the prep-repacked global blob (L2-hot);
    // f broadcast from LDS. Partials -> ZP, reduce+gelu on wave 0.
    {
        const int c = (lane < 50) ? lane : 49;
        float a = (wave == 0) ? lb1[c] : 0.0f;
        const int j0 = wave * 12;
        #pragma unroll
        for (int j4 = 0; j4 < 12; j4++) {
            float4 w = twb[(j0 + j4) * 50 + c];
            float4 f = *(const float4*)&smf[FLo + (j0 + j4) * 4];
            a = fmaf(w.x, f.x, fmaf(w.y, f.y, fmaf(w.z, f.z, fmaf(w.w, f.w, a))));
        }
        if (lane < 50) smf[ZPo + wave * 52 + lane] = a;
        // zero Z1/Z2 pad cols 50..51 (read by j4=12 with zero weights; must
        // not be NaN garbage) — done by idle lanes pre-barrier.
        if (wave == 0 && (lane == 50 || lane == 51)) {
            smf[Z1o + lane] = 0.0f;
            smf[Z2o + lane] = 0.0f;
        }
    }
    __syncthreads();

    if (wave == 0) {
        // reduce + gelu -> Z1 (in-wave write-then-read pattern, as tail v3)
        if (lane < 50) {
            float s = smf[ZPo + lane] + smf[ZPo + 52 + lane]
                    + smf[ZPo + 104 + lane] + smf[ZPo + 156 + lane];
            smf[Z1o + lane] = gelu_exact(s);
        }
        {   // linear2: 50 -> 50
            const int c = (lane < 50) ? lane : 49;
            float a = lb2[c];
            #pragma unroll
            for (int j4 = 0; j4 < 13; j4++) {
                float4 w = twb[2400 + j4 * 50 + c];
                float4 zp = *(const float4*)&smf[Z1o + 4 * j4];
                a = fmaf(w.x, zp.x, fmaf(w.y, zp.y, fmaf(w.z, zp.z, fmaf(w.w, zp.w, a))));
            }
            if (lane < 50) smf[Z2o + lane] = gelu_exact(a);
        }
        {   // linear3: 50 -> 15, *100 -> Z[item]
            const int c3 = (lane < 15) ? lane : 14;
            float a = lb3[c3];
            #pragma unroll
            for (int j4 = 0; j4 < 13; j4++) {
                float4 w = twb[3050 + j4 * 15 + c3];
                float4 zp = *(const float4*)&smf[Z2o + 4 * j4];
                a = fmaf(w.x, zp.x, fmaf(w.y, zp.y, fmaf(w.z, zp.z, fmaf(w.w, zp.w, a))));
            }
            if (lane < 15) Z[(size_t)b * 16 + lane] = a * 100.0f;
        }
    }
}

// ---- SVD kernel: ONE LANE PER ITEM (fully parallel Jacobi).
// 8192 items -> 32 blocks x 256.
__global__ void __launch_bounds__(256)
rminet_svd_kernel(const float* __restrict__ Z, float* __restrict__ out, int B)
{
    const int i = blockIdx.x * 256 + threadIdx.x;
    if (i >= B) return;
    const float* zv = Z + (size_t)i * 16;
    float* ob = out + (size_t)i * 15;
    #pragma unroll
    for (int c = 9; c < 15; c++) ob[c] = zv[c];

    const float A00 = zv[0], A01 = zv[1], A02 = zv[2];
    const float A10 = zv[3], A11 = zv[4], A12 = zv[5];
    const float A20 = zv[6], A21 = zv[7], A22 = zv[8];
    float S00 = A00*A00 + A10*A10 + A20*A20;
    float S01 = A00*A01 + A10*A11 + A20*A21;
    float S02 = A00*A02 + A10*A12 + A20*A22;
    float S11 = A01*A01 + A11*A11 + A21*A21;
    float S12 = A01*A02 + A11*A12 + A21*A22;
    float S22 = A02*A02 + A12*A12 + A22*A22;
    float V00=1.f, V01=0.f, V02=0.f;
    float V10=0.f, V11=1.f, V12=0.f;
    float V20=0.f, V21=0.f, V22=1.f;
    #pragma unroll
    for (int sweep = 0; sweep < 8; sweep++) {
        JROT(S00, S11, S01, S02, S12, V00, V01, V10, V11, V20, V21)
        JROT(S00, S22, S02, S01, S12, V00, V02, V10, V12, V20, V22)
        JROT(S11, S22, S12, S01, S02, V01, V02, V11, V12, V21, V22)
    }
    float e0 = S00, e1 = S11, e2 = S22;
    float va0=V00, va1=V10, va2=V20;
    float vb0=V01, vb1=V11, vb2=V21;
    float vc0=V02, vc1=V12, vc2=V22;
    float sgn = 1.0f, tq;
    if (e0 < e1) { tq=e0;e0=e1;e1=tq; tq=va0;va0=vb0;vb0=tq; tq=va1;va1=vb1;vb1=tq; tq=va2;va2=vb2;vb2=tq; sgn=-sgn; }
    if (e1 < e2) { tq=e1;e1=e2;e2=tq; tq=vb0;vb0=vc0;vc0=tq; tq=vb1;vb1=vc1;vc1=tq; tq=vb2;vb2=vc2;vc2=tq; sgn=-sgn; }
    if (e0 < e1) { tq=e0;e0=e1;e1=tq; tq=va0;va0=vb0;vb0=tq; tq=va1;va1=vb1;vb1=tq; tq=va2;va2=vb2;vb2=tq; sgn=-sgn; }
    vc0 *= sgn; vc1 *= sgn; vc2 *= sgn;
    float u10 = A00*va0 + A01*va1 + A02*va2;
    float u11 = A10*va0 + A11*va1 + A12*va2;
    float u12 = A20*va0 + A21*va1 + A22*va2;
    float n1 = sqrtf(u10*u10 + u11*u11 + u12*u12);
    float rn1 = (n1 > 1e-20f) ? 1.0f / n1 : 0.0f;
    u10 *= rn1; u11 *= rn1; u12 *= rn1;
    float u20 = A00*vb0 + A01*vb1 + A02*vb2;
    float u21 = A10*vb0 + A11*vb1 + A12*vb2;
    float u22 = A20*vb0 + A21*vb1 + A22*vb2;
    float d12 = u20*u10 + u21*u11 + u22*u12;
    u20 -= d12*u10; u21 -= d12*u11; u22 -= d12*u12;
    float n2 = sqrtf(u20*u20 + u21*u21 + u22*u22);
    float rn2 = (n2 > 1e-20f) ? 1.0f / n2 : 0.0f;
    u20 *= rn2; u21 *= rn2; u22 *= rn2;
    float u30 = u11*u22 - u12*u21;
    float u31 = u12*u20 - u10*u22;
    float u32 = u10*u21 - u11*u20;
    ob[0] = u10*va0 + u20*vb0 + u30*vc0;
    ob[1] = u10*va1 + u20*vb1 + u30*vc1;
    ob[2] = u10*va2 + u20*vb2 + u30*vc2;
    ob[3] = u11*va0 + u21*vb0 + u31*vc0;
    ob[4] = u11*va1 + u21*vb1 + u31*vc1;
    ob[5] = u11*va2 + u21*vb2 + u31*vc2;
    ob[6] = u12*va0 + u22*vb0 + u32*vc0;
    ob[7] = u12*va1 + u22*vb1 + u32*vc1;
    ob[8] = u12*va2 + u22*vb2 + u32*vc2;
}

extern "C" void kernel_launch(void* const* d_in, const int* in_sizes, int n_in,
                              void* d_out, int out_size, void* d_ws, size_t ws_size,
                              hipStream_t stream) {
    (void)n_in; (void)out_size; (void)ws_size;
    const float* x     = (const float*)d_in[0];
    const float* calib = (const float*)d_in[1];
    const float* biasv = (const float*)d_in[2];
    const float* cw1   = (const float*)d_in[3];
    const float* cb1   = (const float*)d_in[4];
    const float* cw2   = (const float*)d_in[5];
    const float* cb2   = (const float*)d_in[6];
    const float* cw3   = (const float*)d_in[7];
    const float* cb3   = (const float*)d_in[8];
    const float* cw4   = (const float*)d_in[9];
    const float* cb4   = (const float*)d_in[10];
    const float* lw1   = (const float*)d_in[11];
    const float* lb1   = (const float*)d_in[12];
    const float* lw2   = (const float*)d_in[13];
    const float* lb2   = (const float*)d_in[14];
    const float* lw3   = (const float*)d_in[15];
    const float* lb3   = (const float*)d_in[16];
    float* out = (float*)d_out;
    ushort_t* wsh = (ushort_t*)d_ws;
    float4* twb = (float4*)((char*)d_ws + WS_TWB_BYTE);
    float* Zb   = (float*)((char*)d_ws + WS_Z_BYTE);
    const int B = in_sizes[0] / 1400;

    hipLaunchKernelGGL(prep_kernel, dim3(34), dim3(512), 0, stream,
                       cw1, cw2, cw3, cw4, lw1, lw2, lw3, wsh, twb);
    hipLaunchKernelGGL(rminet_conv_kernel, dim3(B), dim3(NTHREADS), 0, stream,
                       x, calib, biasv, cb1, cb2, cb3, cb4,
                       (const ushort_t*)wsh, (const float4*)twb,
                       lb1, lb2, lb3, Zb);
    hipLaunchKernelGGL(rminet_svd_kernel, dim3((B + 255) / 256), dim3(256), 0, stream,
                       (const float*)Zb, out, B);
}